// Round 28
// baseline (60.198 us; speedup 1.0000x reference)
//
#include <hip/hip_runtime.h>
#include <hip/hip_bf16.h>
#include <stdint.h>

#define VOCAB 50257
#define HID 512
#define LABELS 64
#define TILEV 64
#define NTILES ((VOCAB + TILEV - 1) / TILEV)   // 786
#define BP 520             // B row pitch in ushorts (512 h + 8 pad) = 1040 B

typedef __attribute__((ext_vector_type(8))) short bf16x8;
typedef __attribute__((ext_vector_type(4))) float f32x4;

__device__ __forceinline__ ushort f2bf(float x) {
    uint32_t u = __float_as_uint(x);
    return (ushort)((u + 0x7fffu + ((u >> 16) & 1u)) >> 16);   // RNE
}

__device__ __forceinline__ bf16x8 ld_frag(const ushort* p) {  // p 8B-aligned
    union { uint2 u[2]; bf16x8 v; } x;
    x.u[0] = *(const uint2*)(p);
    x.u[1] = *(const uint2*)(p + 4);
    return x.v;
}

// ---------------------------------------------------------------------------
// K1: M[v][l] = sum_{h=0..511} w1[h,v]*w2[l,h], bf16 MFMA, LABEL-SPLIT.
// KSPLIT=1 via label halves: block b -> vtile=b>>1 (64 v), lhalf=b&1 (32 l),
// FULL K=512. No partial tables: final values written once (12.9 MB, was
// 25.7 partials + gather reduction). Adjacent blocks 2k/2k+1 share the same
// w1 columns -> second read L2-hot; w1 (103MB) < L3 (256MB) regardless.
// Inner structure = R14/R23 (direct-A global->reg, B-in-LDS bf16, one
// barrier, same MFMA/store mapping — hardware-verified 4x). Per wave:
// 32v x 32l = 2x2 frags, 4 MFMA per 32-h chunk, 16 chunks.
// Bias merged as block index 2*NTILES (R23-verified).
// ---------------------------------------------------------------------------
#define MFMA_B16(a, b, c) __builtin_amdgcn_mfma_f32_16x16x32_bf16(a, b, c, 0, 0, 0)

#define PACK8(ar, dst)                                                        \
    {                                                                         \
        union { uint32_t u[4]; bf16x8 v; } _x;                                \
        _Pragma("unroll")                                                     \
        for (int j = 0; j < 4; ++j)                                           \
            _x.u[j] = (uint32_t)f2bf(ar[2 * j]) |                             \
                      ((uint32_t)f2bf(ar[2 * j + 1]) << 16);                  \
        dst = _x.v;                                                           \
    }

#define STORE_ONE(accv, m, n)                                                 \
    {                                                                         \
        int vb = v0 + wv * 32 + (m) * 16 + kg * 4;                            \
        int l  = lbase + (n) * 16 + lrow;                                     \
        _Pragma("unroll")                                                     \
        for (int rr = 0; rr < 4; ++rr)                                        \
            if (fullA || (vb + rr) < VOCAB)                                   \
                M[(size_t)(vb + rr) * LABELS + l] = accv[rr];                 \
    }

__global__ __launch_bounds__(128) void build_mfma(
    const float* __restrict__ w1,   // [HID][VOCAB]
    const float* __restrict__ w2,   // [LABELS][HID]
    const float* __restrict__ b1,   // [HID]
    const float* __restrict__ b2,   // [LABELS]
    float* __restrict__ M,          // [VOCAB][LABELS] final table
    float* __restrict__ C)          // [LABELS] combined bias
{
    const int t = threadIdx.x;      // 0..127
    const int b = blockIdx.x;

    // ---- merged bias block (last block) ----
    if (b == 2 * NTILES) {
        if (t < LABELS) {
            float s = b2[t];
            for (int h = 0; h < HID; h += 4) {
                float4 wv4 = *(const float4*)&w2[t * HID + h];
                float4 bv4 = *(const float4*)&b1[h];
                s += wv4.x * bv4.x + wv4.y * bv4.y + wv4.z * bv4.z + wv4.w * bv4.w;
            }
            C[t] = s;
        }
        return;
    }

    __shared__ ushort lB[32 * BP];  // [l(32)][h(512)] bf16, ~33 KB

    const int vt    = b >> 1;       // vocab tile
    const int lh    = b & 1;        // label half
    const int lane  = t & 63;
    const int wv    = t >> 6;       // wave 0..1 -> v-rows wv*32..+31
    const int lrow  = lane & 15;
    const int kg    = lane >> 4;
    const int v0    = vt * TILEV;
    const int lbase = lh * 32;
    const bool fullA = (v0 + TILEV <= VOCAB);

    const int vA0 = v0 + wv * 32 + lrow;
    const int vA1 = vA0 + 16;
    const bool ok0 = fullA || (vA0 < VOCAB);
    const bool ok1 = fullA || (vA1 < VOCAB);

    // ---- stage B once: 32l x 512h fp32 -> bf16. 32 float4 per thread.
#pragma unroll
    for (int i = 0; i < 32; ++i) {
        int e  = t + 128 * i;       // 0..4095
        int l  = e >> 7;            // 0..31
        int hq = e & 127;           // float4 index within row
        float4 wv4 = *(const float4*)&w2[(lbase + l) * HID + hq * 4];
        uint32_t q0 = (uint32_t)f2bf(wv4.x) | ((uint32_t)f2bf(wv4.y) << 16);
        uint32_t q1 = (uint32_t)f2bf(wv4.z) | ((uint32_t)f2bf(wv4.w) << 16);
        *(uint32_t*)&lB[l * BP + hq * 4]     = q0;
        *(uint32_t*)&lB[l * BP + hq * 4 + 2] = q1;
    }
    __syncthreads();                // the only barrier

    f32x4 acc00 = {0,0,0,0}, acc01 = {0,0,0,0};
    f32x4 acc10 = {0,0,0,0}, acc11 = {0,0,0,0};

#pragma unroll 2
    for (int c = 0; c < HID / 32; ++c) {   // 16 chunks of 32 h
        float ar0[8], ar1[8];
        {
            const float* g = &w1[(size_t)(c * 32 + kg * 8) * VOCAB];
#pragma unroll
            for (int j = 0; j < 8; ++j)
                ar0[j] = ok0 ? g[(size_t)j * VOCAB + vA0] : 0.f;
#pragma unroll
            for (int j = 0; j < 8; ++j)
                ar1[j] = ok1 ? g[(size_t)j * VOCAB + vA1] : 0.f;
        }
        bf16x8 a0, a1;
        PACK8(ar0, a0);
        PACK8(ar1, a1);
        const ushort* bb = &lB[lrow * BP + c * 32 + kg * 8];
        bf16x8 b0  = ld_frag(bb);
        bf16x8 b1f = ld_frag(bb + 16 * BP);
        acc00 = MFMA_B16(a0, b0, acc00);  acc01 = MFMA_B16(a0, b1f, acc01);
        acc10 = MFMA_B16(a1, b0, acc10);  acc11 = MFMA_B16(a1, b1f, acc11);
    }

    STORE_ONE(acc00, 0, 0); STORE_ONE(acc01, 0, 1);
    STORE_ONE(acc10, 1, 0); STORE_ONE(acc11, 1, 1);
}

// ---------------------------------------------------------------------------
// K2: out[tok][l] = M[idx[tok]][l] + bias[l]   (single table, no reduction)
// ---------------------------------------------------------------------------
__global__ __launch_bounds__(256) void gather_out(
    const int* __restrict__ idx,
    const float* __restrict__ M,
    const float* __restrict__ bias,
    float* __restrict__ out,
    int ntok)
{
    int g   = blockIdx.x * 256 + threadIdx.x;
    int tok = g >> 4;
    int j   = g & 15;
    if (tok >= ntok) return;
    int v = idx[tok];
    float4 s = ((const float4*)bias)[j];
    float4 m = ((const float4*)M)[(size_t)v * 16 + j];
    ((float4*)out)[(size_t)tok * 16 + j] =
        make_float4(s.x + m.x, s.y + m.y, s.z + m.z, s.w + m.w);
}

// ---------------------------------------------------------------------------
// Fallback (ws too small for the table): direct per-token dot.
// ---------------------------------------------------------------------------
__global__ __launch_bounds__(256) void direct_kernel(
    const int* __restrict__ idx,
    const float* __restrict__ w1,
    const float* __restrict__ b1,
    const float* __restrict__ w2,
    const float* __restrict__ b2,
    float* __restrict__ out,
    int ntok)
{
    int g   = blockIdx.x * 256 + threadIdx.x;
    int tok = g >> 6;
    int l   = g & 63;
    if (tok >= ntok) return;
    int v = idx[tok];
    float acc = b2[l];
    for (int h = 0; h < HID; ++h)
        acc += (w1[(size_t)h * VOCAB + v] + b1[h]) * w2[l * HID + h];
    out[(size_t)tok * 64 + l] = acc;
}

extern "C" void kernel_launch(void* const* d_in, const int* in_sizes, int n_in,
                              void* d_out, int out_size, void* d_ws, size_t ws_size,
                              hipStream_t stream) {
    const int*   idx = (const int*)d_in[0];
    const float* w1  = (const float*)d_in[1];
    const float* b1  = (const float*)d_in[2];
    const float* w2  = (const float*)d_in[3];
    const float* b2  = (const float*)d_in[4];
    float* out = (float*)d_out;
    const int ntok = in_sizes[0];   // 8*4096 = 32768

    const size_t table_bytes = (size_t)VOCAB * LABELS * sizeof(float);  // ~12.9 MB
    const int nblk2 = (ntok * 16 + 255) / 256;                          // 2048

    if (ws_size >= table_bytes + 1024) {
        // fast path: label-split KSPLIT=1 MFMA build (final table) + bias
        float* M = (float*)d_ws;
        float* C = (float*)((char*)d_ws + table_bytes);
        build_mfma<<<2 * NTILES + 1, 128, 0, stream>>>(w1, w2, b1, b2, M, C);
        gather_out<<<nblk2, 256, 0, stream>>>(idx, M, C, out, ntok);
    } else {
        int nblk = (ntok * 64 + 255) / 256;
        direct_kernel<<<nblk, 256, 0, stream>>>(idx, w1, b1, w2, b2, out, ntok);
    }
}

// Round 29
// 41.487 us; speedup vs baseline: 1.4510x; 1.4510x over previous
//
#include <hip/hip_runtime.h>
#include <hip/hip_bf16.h>
#include <stdint.h>

#define VOCAB 50257
#define HID 512
#define LABELS 64
#define KSPLIT 2
#define KLEN 256           // HID / KSPLIT
#define TILEV 64
#define NTILES ((VOCAB + TILEV - 1) / TILEV)   // 786
#define BP 264             // B row pitch in ushorts (256 h + 8 pad) = 528 B

typedef __attribute__((ext_vector_type(8))) short bf16x8;
typedef __attribute__((ext_vector_type(4))) float f32x4;

__device__ __forceinline__ ushort f2bf(float x) {
    uint32_t u = __float_as_uint(x);
    return (ushort)((u + 0x7fffu + ((u >> 16) & 1u)) >> 16);   // RNE
}

__device__ __forceinline__ float bflo(uint32_t u) {   // low ushort -> float
    return __uint_as_float(u << 16);
}
__device__ __forceinline__ float bfhi(uint32_t u) {   // high ushort -> float
    return __uint_as_float(u & 0xffff0000u);
}

__device__ __forceinline__ bf16x8 ld_frag(const ushort* p) {  // p 8B-aligned
    union { uint2 u[2]; bf16x8 v; } x;
    x.u[0] = *(const uint2*)(p);
    x.u[1] = *(const uint2*)(p + 4);
    return x.v;
}

// ---------------------------------------------------------------------------
// K1: P[s][v][l] = sum_{h in split s} w1[h,v]*w2[l,h], bf16 MFMA, KSPLIT=2.
// EXACTLY the R23-measured-best structure (43.8us: w1 read once, grid
// (786,2)+bias block, direct-A global->reg, B-in-LDS bf16, one barrier,
// 5x-hardware-verified MFMA/store mapping). Single delta vs R23:
// partial tables stored BF16 (ushort) -> WRITE 25.7->12.9 MB, gather
// partial-reads 16.8->8.4 MB. Partials are already bf16-operand products;
// storage rounding adds <=0.2% relative (absmax ~<=5e-4 expected).
// ---------------------------------------------------------------------------
#define MFMA_B16(a, b, c) __builtin_amdgcn_mfma_f32_16x16x32_bf16(a, b, c, 0, 0, 0)

#define PACK8(ar, dst)                                                        \
    {                                                                         \
        union { uint32_t u[4]; bf16x8 v; } _x;                                \
        _Pragma("unroll")                                                     \
        for (int j = 0; j < 4; ++j)                                           \
            _x.u[j] = (uint32_t)f2bf(ar[2 * j]) |                             \
                      ((uint32_t)f2bf(ar[2 * j + 1]) << 16);                  \
        dst = _x.v;                                                           \
    }

#define STORE_ONE(accv, m, n)                                                 \
    {                                                                         \
        int vb = v0 + wv * 32 + (m) * 16 + kg * 4;                            \
        int l  = (n) * 16 + lrow;                                             \
        _Pragma("unroll")                                                     \
        for (int rr = 0; rr < 4; ++rr)                                        \
            if (fullA || (vb + rr) < VOCAB)                                   \
                Pout[(size_t)(vb + rr) * LABELS + l] = f2bf(accv[rr]);        \
    }

__global__ __launch_bounds__(128) void build_mfma(
    const float* __restrict__ w1,   // [HID][VOCAB]
    const float* __restrict__ w2,   // [LABELS][HID]
    const float* __restrict__ b1,   // [HID]
    const float* __restrict__ b2,   // [LABELS]
    ushort* __restrict__ P,         // [KSPLIT][VOCAB][LABELS] bf16 partials
    float* __restrict__ C)          // [LABELS] combined bias (fp32, exact)
{
    const int t = threadIdx.x;      // 0..127

    // ---- merged bias block (R23-verified) ----
    if (blockIdx.x == NTILES) {
        if (blockIdx.y == 0 && t < LABELS) {
            float s = b2[t];
            for (int h = 0; h < HID; h += 4) {
                float4 wv4 = *(const float4*)&w2[t * HID + h];
                float4 bv4 = *(const float4*)&b1[h];
                s += wv4.x * bv4.x + wv4.y * bv4.y + wv4.z * bv4.z + wv4.w * bv4.w;
            }
            C[t] = s;
        }
        return;
    }

    __shared__ ushort lB[LABELS * BP];     // [l][h] bf16 w2 K-slice (~33 KB)

    const int lane  = t & 63;
    const int wv    = t >> 6;       // wave 0..1 -> v-rows wv*32..+31
    const int lrow  = lane & 15;
    const int kg    = lane >> 4;
    const int v0    = blockIdx.x * TILEV;
    const int hbase = blockIdx.y * KLEN;
    ushort* Pout = P + (size_t)blockIdx.y * VOCAB * LABELS;
    const bool fullA = (v0 + TILEV <= VOCAB);

    const int vA0 = v0 + wv * 32 + lrow;
    const int vA1 = vA0 + 16;
    const bool ok0 = fullA || (vA0 < VOCAB);
    const bool ok1 = fullA || (vA1 < VOCAB);

    // ---- stage B once: 64l x 256h fp32 -> bf16. 32 float4 per thread.
#pragma unroll
    for (int i = 0; i < 32; ++i) {
        int e  = t + 128 * i;       // 0..4095
        int l  = e >> 6;            // 0..63
        int hq = e & 63;            // float4 index within row
        float4 wv4 = *(const float4*)&w2[l * HID + hbase + hq * 4];
        uint32_t q0 = (uint32_t)f2bf(wv4.x) | ((uint32_t)f2bf(wv4.y) << 16);
        uint32_t q1 = (uint32_t)f2bf(wv4.z) | ((uint32_t)f2bf(wv4.w) << 16);
        *(uint32_t*)&lB[l * BP + hq * 4]     = q0;
        *(uint32_t*)&lB[l * BP + hq * 4 + 2] = q1;
    }
    __syncthreads();                // the only barrier

    f32x4 acc00 = {0,0,0,0}, acc01 = {0,0,0,0}, acc02 = {0,0,0,0}, acc03 = {0,0,0,0};
    f32x4 acc10 = {0,0,0,0}, acc11 = {0,0,0,0}, acc12 = {0,0,0,0}, acc13 = {0,0,0,0};

#pragma unroll 2
    for (int c = 0; c < KLEN / 32; ++c) {   // 8 chunks
        float ar0[8], ar1[8];
        {
            const float* g = &w1[(size_t)(hbase + c * 32 + kg * 8) * VOCAB];
#pragma unroll
            for (int j = 0; j < 8; ++j)
                ar0[j] = ok0 ? g[(size_t)j * VOCAB + vA0] : 0.f;
#pragma unroll
            for (int j = 0; j < 8; ++j)
                ar1[j] = ok1 ? g[(size_t)j * VOCAB + vA1] : 0.f;
        }
        bf16x8 a0, a1;
        PACK8(ar0, a0);
        PACK8(ar1, a1);
        const ushort* bb = &lB[lrow * BP + c * 32 + kg * 8];
        bf16x8 b0  = ld_frag(bb);
        bf16x8 b1f = ld_frag(bb + 16 * BP);
        bf16x8 b2f = ld_frag(bb + 32 * BP);
        bf16x8 b3f = ld_frag(bb + 48 * BP);
        acc00 = MFMA_B16(a0, b0, acc00);  acc01 = MFMA_B16(a0, b1f, acc01);
        acc02 = MFMA_B16(a0, b2f, acc02); acc03 = MFMA_B16(a0, b3f, acc03);
        acc10 = MFMA_B16(a1, b0, acc10);  acc11 = MFMA_B16(a1, b1f, acc11);
        acc12 = MFMA_B16(a1, b2f, acc12); acc13 = MFMA_B16(a1, b3f, acc13);
    }

    STORE_ONE(acc00, 0, 0); STORE_ONE(acc01, 0, 1);
    STORE_ONE(acc02, 0, 2); STORE_ONE(acc03, 0, 3);
    STORE_ONE(acc10, 1, 0); STORE_ONE(acc11, 1, 1);
    STORE_ONE(acc12, 1, 2); STORE_ONE(acc13, 1, 3);
}

// ---------------------------------------------------------------------------
// K2: out[tok][l] = sum_s bf16 P[s][idx[tok]][l] + bias[l]
// 16 threads/token, each: 2x uint2 (4 bf16) per partial + fp32 bias + store.
// ---------------------------------------------------------------------------
__global__ __launch_bounds__(256) void gather_out(
    const int* __restrict__ idx,
    const ushort* __restrict__ P,
    const float* __restrict__ bias,
    float* __restrict__ out,
    int ntok)
{
    int g   = blockIdx.x * 256 + threadIdx.x;
    int tok = g >> 4;
    int j   = g & 15;
    if (tok >= ntok) return;
    int v = idx[tok];
    float4 s = ((const float4*)bias)[j];
    const ushort* p0 = P + (size_t)v * LABELS + j * 4;
    const ushort* p1 = p0 + (size_t)VOCAB * LABELS;
    uint2 a = *(const uint2*)p0;
    uint2 b = *(const uint2*)p1;
    s.x += bflo(a.x) + bflo(b.x);
    s.y += bfhi(a.x) + bfhi(b.x);
    s.z += bflo(a.y) + bflo(b.y);
    s.w += bfhi(a.y) + bfhi(b.y);
    ((float4*)out)[(size_t)tok * 16 + j] = s;
}

// ---------------------------------------------------------------------------
// Fallback (ws too small for the tables): direct per-token dot.
// ---------------------------------------------------------------------------
__global__ __launch_bounds__(256) void direct_kernel(
    const int* __restrict__ idx,
    const float* __restrict__ w1,
    const float* __restrict__ b1,
    const float* __restrict__ w2,
    const float* __restrict__ b2,
    float* __restrict__ out,
    int ntok)
{
    int g   = blockIdx.x * 256 + threadIdx.x;
    int tok = g >> 6;
    int l   = g & 63;
    if (tok >= ntok) return;
    int v = idx[tok];
    float acc = b2[l];
    for (int h = 0; h < HID; ++h)
        acc += (w1[(size_t)h * VOCAB + v] + b1[h]) * w2[l * HID + h];
    out[(size_t)tok * 64 + l] = acc;
}

extern "C" void kernel_launch(void* const* d_in, const int* in_sizes, int n_in,
                              void* d_out, int out_size, void* d_ws, size_t ws_size,
                              hipStream_t stream) {
    const int*   idx = (const int*)d_in[0];
    const float* w1  = (const float*)d_in[1];
    const float* b1  = (const float*)d_in[2];
    const float* w2  = (const float*)d_in[3];
    const float* b2  = (const float*)d_in[4];
    float* out = (float*)d_out;
    const int ntok = in_sizes[0];   // 8*4096 = 32768

    const size_t ptab_bytes = (size_t)KSPLIT * VOCAB * LABELS * sizeof(ushort); // ~12.9 MB
    const int nblk2 = (ntok * 16 + 255) / 256;                                  // 2048

    if (ws_size >= ptab_bytes + 1024) {
        // fast path: KSPLIT=2 MFMA build, bf16 partials, merged bias block
        ushort* P = (ushort*)d_ws;
        float*  C = (float*)((char*)d_ws + ptab_bytes);
        dim3 grid1(NTILES + 1, KSPLIT);                    // 787 x 2 (last x = bias)
        build_mfma<<<grid1, 128, 0, stream>>>(w1, w2, b1, b2, P, C);
        gather_out<<<nblk2, 256, 0, stream>>>(idx, P, C, out, ntok);
    } else {
        int nblk = (ntok * 64 + 255) / 256;
        direct_kernel<<<nblk, 256, 0, stream>>>(idx, w1, b1, w2, b2, out, ntok);
    }
}

// Round 30
// 40.393 us; speedup vs baseline: 1.4903x; 1.0271x over previous
//
#include <hip/hip_runtime.h>
#include <hip/hip_bf16.h>
#include <stdint.h>

#define VOCAB 50257
#define HID 512
#define LABELS 64
#define KSPLIT 2
#define KLEN 256           // HID / KSPLIT
#define TILEV 64
#define NTILES ((VOCAB + TILEV - 1) / TILEV)   // 786
#define BP 264             // B row pitch in ushorts (256 h + 8 pad) = 528 B

typedef __attribute__((ext_vector_type(8))) short bf16x8;
typedef __attribute__((ext_vector_type(4))) float f32x4;

__device__ __forceinline__ ushort f2bf(float x) {
    uint32_t u = __float_as_uint(x);
    return (ushort)((u + 0x7fffu + ((u >> 16) & 1u)) >> 16);   // RNE
}

__device__ __forceinline__ float bflo(uint32_t u) {   // low ushort -> float
    return __uint_as_float(u << 16);
}
__device__ __forceinline__ float bfhi(uint32_t u) {   // high ushort -> float
    return __uint_as_float(u & 0xffff0000u);
}

__device__ __forceinline__ bf16x8 ld_frag(const ushort* p) {  // p 8B-aligned
    union { uint2 u[2]; bf16x8 v; } x;
    x.u[0] = *(const uint2*)(p);
    x.u[1] = *(const uint2*)(p + 4);
    return x.v;
}

// ---------------------------------------------------------------------------
// K1: P[s][v][l] = sum_{h in split s} w1[h,v]*w2[l,h], bf16 MFMA, KSPLIT=2.
// R29 structure (41.5us: w1 read once, bf16 partials, merged bias) with ONE
// delta: 256-thread / 4-wave blocks. Each wave owns a quadrant
// (vhalf=wv&1 -> 32v, lhalf=wv>>1 -> 32l): 2 A-frags x 2 B-frags,
// 4 MFMA/chunk. Same grid (786,2), same 33KB LDS now shared by 4 waves ->
// waves/CU doubles 8->16, halving latency exposure (build was 17.5% occ,
// 1.34 TB/s vs 6.3 floor). Store mapping = R28/R29-verified (lbase offset).
// ---------------------------------------------------------------------------
#define MFMA_B16(a, b, c) __builtin_amdgcn_mfma_f32_16x16x32_bf16(a, b, c, 0, 0, 0)

#define PACK8(ar, dst)                                                        \
    {                                                                         \
        union { uint32_t u[4]; bf16x8 v; } _x;                                \
        _Pragma("unroll")                                                     \
        for (int j = 0; j < 4; ++j)                                           \
            _x.u[j] = (uint32_t)f2bf(ar[2 * j]) |                             \
                      ((uint32_t)f2bf(ar[2 * j + 1]) << 16);                  \
        dst = _x.v;                                                           \
    }

#define STORE_ONE(accv, m, n)                                                 \
    {                                                                         \
        int vb = v0 + vhalf * 32 + (m) * 16 + kg * 4;                         \
        int l  = lbase + (n) * 16 + lrow;                                     \
        _Pragma("unroll")                                                     \
        for (int rr = 0; rr < 4; ++rr)                                        \
            if (fullA || (vb + rr) < VOCAB)                                   \
                Pout[(size_t)(vb + rr) * LABELS + l] = f2bf(accv[rr]);        \
    }

__global__ __launch_bounds__(256) void build_mfma(
    const float* __restrict__ w1,   // [HID][VOCAB]
    const float* __restrict__ w2,   // [LABELS][HID]
    const float* __restrict__ b1,   // [HID]
    const float* __restrict__ b2,   // [LABELS]
    ushort* __restrict__ P,         // [KSPLIT][VOCAB][LABELS] bf16 partials
    float* __restrict__ C)          // [LABELS] combined bias (fp32, exact)
{
    const int t = threadIdx.x;      // 0..255

    // ---- merged bias block (R23/R29-verified) ----
    if (blockIdx.x == NTILES) {
        if (blockIdx.y == 0 && t < LABELS) {
            float s = b2[t];
            for (int h = 0; h < HID; h += 4) {
                float4 wv4 = *(const float4*)&w2[t * HID + h];
                float4 bv4 = *(const float4*)&b1[h];
                s += wv4.x * bv4.x + wv4.y * bv4.y + wv4.z * bv4.z + wv4.w * bv4.w;
            }
            C[t] = s;
        }
        return;
    }

    __shared__ ushort lB[LABELS * BP];     // [l][h] bf16 w2 K-slice (~33 KB)

    const int lane  = t & 63;
    const int wv    = t >> 6;       // wave 0..3
    const int vhalf = wv & 1;       // v-rows vhalf*32..+31
    const int lhalf = wv >> 1;      // labels lhalf*32..+31
    const int lrow  = lane & 15;
    const int kg    = lane >> 4;
    const int v0    = blockIdx.x * TILEV;
    const int hbase = blockIdx.y * KLEN;
    const int lbase = lhalf * 32;
    ushort* Pout = P + (size_t)blockIdx.y * VOCAB * LABELS;
    const bool fullA = (v0 + TILEV <= VOCAB);

    const int vA0 = v0 + vhalf * 32 + lrow;
    const int vA1 = vA0 + 16;
    const bool ok0 = fullA || (vA0 < VOCAB);
    const bool ok1 = fullA || (vA1 < VOCAB);

    // ---- stage B once: 64l x 256h fp32 -> bf16. 16 float4 per thread.
#pragma unroll
    for (int i = 0; i < 16; ++i) {
        int e  = t + 256 * i;       // 0..4095
        int l  = e >> 6;            // 0..63
        int hq = e & 63;            // float4 index within row
        float4 wv4 = *(const float4*)&w2[l * HID + hbase + hq * 4];
        uint32_t q0 = (uint32_t)f2bf(wv4.x) | ((uint32_t)f2bf(wv4.y) << 16);
        uint32_t q1 = (uint32_t)f2bf(wv4.z) | ((uint32_t)f2bf(wv4.w) << 16);
        *(uint32_t*)&lB[l * BP + hq * 4]     = q0;
        *(uint32_t*)&lB[l * BP + hq * 4 + 2] = q1;
    }
    __syncthreads();                // the only barrier

    f32x4 acc00 = {0,0,0,0}, acc01 = {0,0,0,0};
    f32x4 acc10 = {0,0,0,0}, acc11 = {0,0,0,0};

#pragma unroll 2
    for (int c = 0; c < KLEN / 32; ++c) {   // 8 chunks
        float ar0[8], ar1[8];
        {
            const float* g = &w1[(size_t)(hbase + c * 32 + kg * 8) * VOCAB];
#pragma unroll
            for (int j = 0; j < 8; ++j)
                ar0[j] = ok0 ? g[(size_t)j * VOCAB + vA0] : 0.f;
#pragma unroll
            for (int j = 0; j < 8; ++j)
                ar1[j] = ok1 ? g[(size_t)j * VOCAB + vA1] : 0.f;
        }
        bf16x8 a0, a1;
        PACK8(ar0, a0);
        PACK8(ar1, a1);
        const ushort* bb = &lB[(lbase + lrow) * BP + c * 32 + kg * 8];
        bf16x8 b0  = ld_frag(bb);
        bf16x8 b1f = ld_frag(bb + 16 * BP);
        acc00 = MFMA_B16(a0, b0, acc00);  acc01 = MFMA_B16(a0, b1f, acc01);
        acc10 = MFMA_B16(a1, b0, acc10);  acc11 = MFMA_B16(a1, b1f, acc11);
    }

    STORE_ONE(acc00, 0, 0); STORE_ONE(acc01, 0, 1);
    STORE_ONE(acc10, 1, 0); STORE_ONE(acc11, 1, 1);
}

// ---------------------------------------------------------------------------
// K2: out[tok][l] = sum_s bf16 P[s][idx[tok]][l] + bias[l]  (R29-verified)
// ---------------------------------------------------------------------------
__global__ __launch_bounds__(256) void gather_out(
    const int* __restrict__ idx,
    const ushort* __restrict__ P,
    const float* __restrict__ bias,
    float* __restrict__ out,
    int ntok)
{
    int g   = blockIdx.x * 256 + threadIdx.x;
    int tok = g >> 4;
    int j   = g & 15;
    if (tok >= ntok) return;
    int v = idx[tok];
    float4 s = ((const float4*)bias)[j];
    const ushort* p0 = P + (size_t)v * LABELS + j * 4;
    const ushort* p1 = p0 + (size_t)VOCAB * LABELS;
    uint2 a = *(const uint2*)p0;
    uint2 b = *(const uint2*)p1;
    s.x += bflo(a.x) + bflo(b.x);
    s.y += bfhi(a.x) + bfhi(b.x);
    s.z += bflo(a.y) + bflo(b.y);
    s.w += bfhi(a.y) + bfhi(b.y);
    ((float4*)out)[(size_t)tok * 16 + j] = s;
}

// ---------------------------------------------------------------------------
// Fallback (ws too small for the tables): direct per-token dot.
// ---------------------------------------------------------------------------
__global__ __launch_bounds__(256) void direct_kernel(
    const int* __restrict__ idx,
    const float* __restrict__ w1,
    const float* __restrict__ b1,
    const float* __restrict__ w2,
    const float* __restrict__ b2,
    float* __restrict__ out,
    int ntok)
{
    int g   = blockIdx.x * 256 + threadIdx.x;
    int tok = g >> 6;
    int l   = g & 63;
    if (tok >= ntok) return;
    int v = idx[tok];
    float acc = b2[l];
    for (int h = 0; h < HID; ++h)
        acc += (w1[(size_t)h * VOCAB + v] + b1[h]) * w2[l * HID + h];
    out[(size_t)tok * 64 + l] = acc;
}

extern "C" void kernel_launch(void* const* d_in, const int* in_sizes, int n_in,
                              void* d_out, int out_size, void* d_ws, size_t ws_size,
                              hipStream_t stream) {
    const int*   idx = (const int*)d_in[0];
    const float* w1  = (const float*)d_in[1];
    const float* b1  = (const float*)d_in[2];
    const float* w2  = (const float*)d_in[3];
    const float* b2  = (const float*)d_in[4];
    float* out = (float*)d_out;
    const int ntok = in_sizes[0];   // 8*4096 = 32768

    const size_t ptab_bytes = (size_t)KSPLIT * VOCAB * LABELS * sizeof(ushort); // ~12.9 MB
    const int nblk2 = (ntok * 16 + 255) / 256;                                  // 2048

    if (ws_size >= ptab_bytes + 1024) {
        // fast path: KSPLIT=2 MFMA build, bf16 partials, 4-wave blocks
        ushort* P = (ushort*)d_ws;
        float*  C = (float*)((char*)d_ws + ptab_bytes);
        dim3 grid1(NTILES + 1, KSPLIT);                    // 787 x 2 (last x = bias)
        build_mfma<<<grid1, 256, 0, stream>>>(w1, w2, b1, b2, P, C);
        gather_out<<<nblk2, 256, 0, stream>>>(idx, P, C, out, ntok);
    } else {
        int nblk = (ntok * 64 + 255) / 256;
        direct_kernel<<<nblk, 256, 0, stream>>>(idx, w1, b1, w2, b2, out, ntok);
    }
}